// Round 1
// 744.074 us; speedup vs baseline: 1.0078x; 1.0078x over previous
//
#include <hip/hip_runtime.h>
#include <math.h>

#define NFEAT 512
#define NHID  128
#define NCLASS 40

// coarse bucket = 512 rows; col packed bits 0..16, rel-row bits 17..25
#define BSH 9
#define BROWS 512
#define COLMASK 0x1FFFF
#define PCHUNK 8192

typedef __bf16 bf16x8 __attribute__((ext_vector_type(8)));
typedef __bf16 bf16x4 __attribute__((ext_vector_type(4)));
typedef float f32x4 __attribute__((ext_vector_type(4)));

// ---------------------------------------------------------------------------
// W1 [512,128] f32 -> Bt [128,512] bf16 (transposed)
// ---------------------------------------------------------------------------
__global__ void convW1_kernel(const float* __restrict__ W1, __bf16* __restrict__ Bt) {
  int i = blockIdx.x * 256 + threadIdx.x;  // 65536
  int kk = i >> 7, nn = i & 127;
  Bt[nn * 512 + kk] = (__bf16)W1[i];
}

// W2 [128,40] f32 -> W2t [48,128] bf16 (transposed, zero-padded cols 40..47)
__global__ void convW2_kernel(const float* __restrict__ W2, __bf16* __restrict__ W2t) {
  int i = blockIdx.x * 256 + threadIdx.x;  // 6144
  int c = i >> 7, k = i & 127;
  W2t[i] = (c < NCLASS) ? (__bf16)W2[k * NCLASS + c] : (__bf16)0.f;
}

// dropout mask {0,2.0} -> bitmask: 1 bit per (row,feature). Exact (2.0 is
// reconstructed as a literal). One wave packs 64 consecutive features.
__global__ __launch_bounds__(256) void packmask_kernel(const float* __restrict__ dmask,
                                                       unsigned long long* __restrict__ dbits,
                                                       int total64) {
  int w = (blockIdx.x * 256 + threadIdx.x) >> 6;
  int lane = threadIdx.x & 63;
  if (w >= total64) return;
  float v = dmask[(size_t)w * 64 + lane];
  unsigned long long b = __ballot(v != 0.f);
  if (lane == 0) dbits[w] = b;
}

// ---------------------------------------------------------------------------
// GEMM1 (tiled MFMA bf16): xwb[n,128] = bf16(X[n,512] @ W1)
// ---------------------------------------------------------------------------
#define ASTR 48
#define BSTR 48
__global__ __launch_bounds__(256) void gemm1_mfma_kernel(const float* __restrict__ X,
                                                         const __bf16* __restrict__ Bt,
                                                         __bf16* __restrict__ xwb, int n) {
  __shared__ __bf16 smem[64 * ASTR + 128 * BSTR];
  __bf16* As = smem;
  __bf16* Bs = smem + 64 * ASTR;

  const int tid = threadIdx.x;
  const int lane = tid & 63;
  const int wid = tid >> 6;
  const int m = lane & 15;
  const int quad = lane >> 4;
  const int row0 = blockIdx.x * 64;

  f32x4 acc[8];
#pragma unroll
  for (int t = 0; t < 8; ++t) acc[t] = (f32x4){0.f, 0.f, 0.f, 0.f};

  const int ar = tid >> 3, aq = tid & 7;
  const int bc = tid >> 2, bq = tid & 3;

  const float4* X4 = (const float4*)X;
  const bf16x8* Bt8 = (const bf16x8*)Bt;
  const float4 z4 = make_float4(0.f, 0.f, 0.f, 0.f);
  const int r1 = row0 + ar, r2 = row0 + 32 + ar;
  const bool ok1 = r1 < n, ok2 = r2 < n;

  float4 a0, a1;
  bf16x8 b0, b1;
  a0 = ok1 ? X4[(size_t)r1 * 128 + aq] : z4;
  a1 = ok2 ? X4[(size_t)r2 * 128 + aq] : z4;
  b0 = Bt8[(size_t)bc * 64 + bq];
  b1 = Bt8[(size_t)(64 + bc) * 64 + bq];

  for (int kt = 0; kt < 16; ++kt) {
    __syncthreads();
    bf16x4 av0, av1;
    av0[0] = (__bf16)a0.x; av0[1] = (__bf16)a0.y; av0[2] = (__bf16)a0.z; av0[3] = (__bf16)a0.w;
    av1[0] = (__bf16)a1.x; av1[1] = (__bf16)a1.y; av1[2] = (__bf16)a1.z; av1[3] = (__bf16)a1.w;
    *(bf16x4*)&As[ar * ASTR + aq * 4] = av0;
    *(bf16x4*)&As[(32 + ar) * ASTR + aq * 4] = av1;
    *(bf16x8*)&Bs[bc * BSTR + bq * 8] = b0;
    *(bf16x8*)&Bs[(64 + bc) * BSTR + bq * 8] = b1;
    __syncthreads();
    if (kt < 15) {
      int ko = (kt + 1) * 8, kc = (kt + 1) * 4;
      a0 = ok1 ? X4[(size_t)r1 * 128 + ko + aq] : z4;
      a1 = ok2 ? X4[(size_t)r2 * 128 + ko + aq] : z4;
      b0 = Bt8[(size_t)bc * 64 + kc + bq];
      b1 = Bt8[(size_t)(64 + bc) * 64 + kc + bq];
    }
    bf16x8 af = *(const bf16x8*)&As[(wid * 16 + m) * ASTR + quad * 8];
#pragma unroll
    for (int t = 0; t < 8; ++t) {
      bf16x8 bfr = *(const bf16x8*)&Bs[(t * 16 + m) * BSTR + quad * 8];
      acc[t] = __builtin_amdgcn_mfma_f32_16x16x32_bf16(af, bfr, acc[t], 0, 0, 0);
    }
  }

  __syncthreads();
  __bf16* cs = smem;  // [64][136]
#pragma unroll
  for (int t = 0; t < 8; ++t)
#pragma unroll
    for (int r = 0; r < 4; ++r)
      cs[(wid * 16 + quad * 4 + r) * 136 + t * 16 + m] = (__bf16)acc[t][r];
  __syncthreads();
  bf16x8* xwv = (bf16x8*)xwb;
#pragma unroll
  for (int i = 0; i < 4; ++i) {
    int p = tid + i * 256;
    int r = p >> 4, c8 = p & 15;
    int gr = row0 + r;
    if (gr < n) xwv[(size_t)gr * 16 + c8] = *(const bf16x8*)&cs[r * 136 + c8 * 8];
  }
}

// ---------------------------------------------------------------------------
// CSR build pass 0: coarse-bucket histogram (LDS-aggregated)
// ---------------------------------------------------------------------------
__global__ __launch_bounds__(256) void hist_kernel(const int* __restrict__ erow,
                                                   int* __restrict__ bhist, int e, int nb2) {
  __shared__ int h[256];
  const int tid = threadIdx.x;
  h[tid] = 0;
  __syncthreads();
  for (int i = blockIdx.x * 256 + tid; i < e; i += gridDim.x * 256)
    atomicAdd(&h[erow[i] >> BSH], 1);
  __syncthreads();
  if (tid < nb2 && h[tid]) atomicAdd(&bhist[tid], h[tid]);
}

// pass 1: scan bucket totals (single block)
__global__ __launch_bounds__(256) void bucketscan_kernel(const int* __restrict__ bhist,
                                                         int* __restrict__ bbase,
                                                         int* __restrict__ bcur,
                                                         int* __restrict__ offs,
                                                         int n, int e, int nb2) {
  __shared__ int s[256];
  const int tid = threadIdx.x;
  int v = (tid < nb2) ? bhist[tid] : 0;
  s[tid] = v;
  __syncthreads();
  for (int off = 1; off < 256; off <<= 1) {
    int x = (tid >= off) ? s[tid - off] : 0;
    __syncthreads();
    s[tid] += x;
    __syncthreads();
  }
  int excl = s[tid] - v;
  if (tid <= nb2) bbase[tid] = excl;
  if (tid < nb2) bcur[tid] = excl;
  if (tid == 0) offs[n] = e;
}

// pass 2: chunked counting-sort partition (grouped writes)
__global__ __launch_bounds__(256) void partition_kernel(const int* __restrict__ erow,
                                                        const int* __restrict__ ecol,
                                                        const float* __restrict__ ew,
                                                        int* __restrict__ bcur,
                                                        int2* __restrict__ tmp, int e, int nb2) {
  __shared__ int hist[256];
  __shared__ int base[256];
  const int tid = threadIdx.x;
  const int b0 = blockIdx.x * PCHUNK;
  hist[tid] = 0;
  int pk[32], meta[32];
  __syncthreads();
#pragma unroll
  for (int i = 0; i < 32; ++i) {
    int idx = b0 + i * 256 + tid;
    if (idx < e) {
      int r = erow[idx];
      int c = ecol[idx];
      int bk = r >> BSH;
      int rk = atomicAdd(&hist[bk], 1);
      pk[i] = c | ((r & (BROWS - 1)) << 17);
      meta[i] = bk | (rk << 8);
    } else {
      meta[i] = -1;
    }
  }
  __syncthreads();
  if (tid < nb2 && hist[tid]) base[tid] = atomicAdd(&bcur[tid], hist[tid]);
  __syncthreads();
#pragma unroll
  for (int i = 0; i < 32; ++i) {
    if (meta[i] >= 0) {
      int bk = meta[i] & 255, rk = meta[i] >> 8;
      int idx = b0 + i * 256 + tid;
      tmp[base[bk] + rk] = make_int2(pk[i], __float_as_int(ew[idx]));
    }
  }
}

// pass 3: one block per coarse bucket -> offs + final CSR
__global__ __launch_bounds__(256) void scatter_kernel(const int* __restrict__ bbase,
                                                      const int2* __restrict__ tmp,
                                                      int2* __restrict__ csr,
                                                      int* __restrict__ offs, int n) {
  __shared__ int rowcnt[BROWS];
  __shared__ int rowptr[BROWS];
  __shared__ int s[256];
  const int b = blockIdx.x, tid = threadIdx.x;
  const int row0 = b << BSH;
  const int s0 = bbase[b], s1 = bbase[b + 1];
  rowcnt[tid] = 0;
  rowcnt[tid + 256] = 0;
  __syncthreads();
  for (int i = s0 + tid; i < s1; i += 256)
    atomicAdd(&rowcnt[(tmp[i].x >> 17) & (BROWS - 1)], 1);
  __syncthreads();
  int c0 = rowcnt[2 * tid], c1 = rowcnt[2 * tid + 1];
  int tsum = c0 + c1;
  s[tid] = tsum;
  __syncthreads();
  for (int off = 1; off < 256; off <<= 1) {
    int x = (tid >= off) ? s[tid - off] : 0;
    __syncthreads();
    s[tid] += x;
    __syncthreads();
  }
  int excl = s0 + s[tid] - tsum;
  __syncthreads();
  rowptr[2 * tid] = excl;
  rowptr[2 * tid + 1] = excl + c0;
  int r0 = row0 + 2 * tid;
  if (r0 < n) offs[r0] = excl;
  if (r0 + 1 < n) offs[r0 + 1] = excl + c0;
  __syncthreads();
  for (int i = s0 + tid; i < s1; i += 256) {
    int2 eu = tmp[i];
    int rel = (eu.x >> 17) & (BROWS - 1);
    int slot = atomicAdd(&rowptr[rel], 1);
    csr[slot] = make_int2(eu.x & COLMASK, eu.y);
  }
}

// ---------------------------------------------------------------------------
// SpMM1 + bias + relu + dropout(bitmask): 8-edge main loop = 4 independent
// csr->gather chains in flight per lane (was 2) to raise gather MLP.
// ---------------------------------------------------------------------------
__global__ __launch_bounds__(256) void spmm1_kernel(const int* __restrict__ offs,
                                                    const int2* __restrict__ csr,
                                                    const __bf16* __restrict__ xwb,
                                                    const float* __restrict__ b1,
                                                    const unsigned int* __restrict__ dbits,
                                                    float* __restrict__ x2, int n) {
  const int lane = threadIdx.x & 63;
  const int wid = threadIdx.x >> 6;
  const int row = blockIdx.x * 4 + wid;
  if (row >= n) return;
  const int s = offs[row], t = offs[row + 1];
  const int half = lane >> 5, sl = lane & 31;
  const bf16x4* xv = (const bf16x4*)xwb;  // row stride 32 chunks
  float a0 = 0.f, a1 = 0.f, a2 = 0.f, a3 = 0.f;
  int j = s;
  for (; j + 7 < t; j += 8) {  // 8 edges: 4 unguarded gathers in flight/lane
    int2 ca = csr[j + half];
    int2 cb = csr[j + 2 + half];
    int2 cc = csr[j + 4 + half];
    int2 cd = csr[j + 6 + half];
    bf16x4 va = xv[(size_t)ca.x * 32 + sl];
    bf16x4 vb = xv[(size_t)cb.x * 32 + sl];
    bf16x4 vc = xv[(size_t)cc.x * 32 + sl];
    bf16x4 vd = xv[(size_t)cd.x * 32 + sl];
    float wa = __int_as_float(ca.y), wb = __int_as_float(cb.y);
    float wc = __int_as_float(cc.y), wd = __int_as_float(cd.y);
    a0 += wa * (float)va[0] + wb * (float)vb[0] + wc * (float)vc[0] + wd * (float)vd[0];
    a1 += wa * (float)va[1] + wb * (float)vb[1] + wc * (float)vc[1] + wd * (float)vd[1];
    a2 += wa * (float)va[2] + wb * (float)vb[2] + wc * (float)vc[2] + wd * (float)vd[2];
    a3 += wa * (float)va[3] + wb * (float)vb[3] + wc * (float)vc[3] + wd * (float)vd[3];
  }
  for (; j + 3 < t; j += 4) {
    int2 ca = csr[j + half];
    int2 cb = csr[j + 2 + half];
    bf16x4 va = xv[(size_t)ca.x * 32 + sl];
    bf16x4 vb = xv[(size_t)cb.x * 32 + sl];
    float wa = __int_as_float(ca.y), wb = __int_as_float(cb.y);
    a0 += wa * (float)va[0] + wb * (float)vb[0];
    a1 += wa * (float)va[1] + wb * (float)vb[1];
    a2 += wa * (float)va[2] + wb * (float)vb[2];
    a3 += wa * (float)va[3] + wb * (float)vb[3];
  }
  for (; j < t; j += 2) {
    int jj = j + half;
    bool ok = jj < t;
    int2 c = csr[ok ? jj : j];
    float w = ok ? __int_as_float(c.y) : 0.f;
    bf16x4 v = xv[(size_t)c.x * 32 + sl];
    a0 += w * (float)v[0];
    a1 += w * (float)v[1];
    a2 += w * (float)v[2];
    a3 += w * (float)v[3];
  }
  a0 += __shfl_xor(a0, 32); a1 += __shfl_xor(a1, 32);
  a2 += __shfl_xor(a2, 32); a3 += __shfl_xor(a3, 32);
  if (half == 0) {
    float4 bb = ((const float4*)b1)[sl];
    unsigned int mw = dbits[(size_t)row * 4 + (sl >> 3)];
    int nib = (mw >> ((sl & 7) * 4)) & 15;
    float4 o;
    o.x = (nib & 1) ? fmaxf(a0 + bb.x, 0.f) * 2.0f : 0.f;
    o.y = (nib & 2) ? fmaxf(a1 + bb.y, 0.f) * 2.0f : 0.f;
    o.z = (nib & 4) ? fmaxf(a2 + bb.z, 0.f) * 2.0f : 0.f;
    o.w = (nib & 8) ? fmaxf(a3 + bb.w, 0.f) * 2.0f : 0.f;
    ((float4*)x2)[(size_t)row * 32 + sl] = o;
  }
}

// ---------------------------------------------------------------------------
// GEMM2 (MFMA bf16): x2wb[n,64pad] = bf16(x2[n,128] @ W2[128,40])
// whole K=128 in LDS; B-frags register-resident from W2t (L2-hot)
// ---------------------------------------------------------------------------
#define A2STR 136
__global__ __launch_bounds__(256) void gemm2_mfma_kernel(const float* __restrict__ x2,
                                                         const __bf16* __restrict__ W2t,
                                                         __bf16* __restrict__ x2wb, int n) {
  __shared__ __bf16 As[64 * A2STR];  // 17408 B
  const int tid = threadIdx.x;
  const int lane = tid & 63;
  const int wid = tid >> 6;
  const int m = lane & 15;
  const int quad = lane >> 4;
  const int row0 = blockIdx.x * 64;

  const bf16x8* Bv = (const bf16x8*)W2t;  // [48][16]
  bf16x8 bfr[3][4];
#pragma unroll
  for (int t = 0; t < 3; ++t)
#pragma unroll
    for (int ks = 0; ks < 4; ++ks)
      bfr[t][ks] = Bv[(t * 16 + m) * 16 + ks * 4 + quad];

  const float4* X4 = (const float4*)x2;  // row stride 32
  const float4 z4 = make_float4(0.f, 0.f, 0.f, 0.f);
#pragma unroll
  for (int i = 0; i < 8; ++i) {
    int p = tid + i * 256;  // 2048 float4 chunks = 64 rows x 32
    int r = p >> 5, q = p & 31;
    int gr = row0 + r;
    float4 a = (gr < n) ? X4[(size_t)gr * 32 + q] : z4;
    bf16x4 av;
    av[0] = (__bf16)a.x; av[1] = (__bf16)a.y; av[2] = (__bf16)a.z; av[3] = (__bf16)a.w;
    *(bf16x4*)&As[r * A2STR + q * 4] = av;
  }
  __syncthreads();

  f32x4 acc[3];
#pragma unroll
  for (int t = 0; t < 3; ++t) acc[t] = (f32x4){0.f, 0.f, 0.f, 0.f};
#pragma unroll
  for (int ks = 0; ks < 4; ++ks) {
    bf16x8 af = *(const bf16x8*)&As[(wid * 16 + m) * A2STR + ks * 32 + quad * 8];
#pragma unroll
    for (int t = 0; t < 3; ++t)
      acc[t] = __builtin_amdgcn_mfma_f32_16x16x32_bf16(af, bfr[t][ks], acc[t], 0, 0, 0);
  }
  __syncthreads();

  // epilogue: LDS bounce [64][64], zero cols 48..63
  __bf16* cs = As;
  {
    bf16x4 z;
    z[0] = z[1] = z[2] = z[3] = (__bf16)0.f;
    *(bf16x4*)&cs[(tid >> 2) * 64 + 48 + (tid & 3) * 4] = z;
  }
#pragma unroll
  for (int t = 0; t < 3; ++t)
#pragma unroll
    for (int r = 0; r < 4; ++r)
      cs[(wid * 16 + quad * 4 + r) * 64 + t * 16 + m] = (__bf16)acc[t][r];
  __syncthreads();
  bf16x8* ov = (bf16x8*)x2wb;  // row stride 8 chunks (128 B)
#pragma unroll
  for (int i = 0; i < 2; ++i) {
    int p = tid + i * 256;  // 512 chunks
    int r = p >> 3, c8 = p & 7;
    int gr = row0 + r;
    if (gr < n) ov[(size_t)gr * 8 + c8] = *(const bf16x8*)&cs[r * 64 + c8 * 8];
  }
}

// ---------------------------------------------------------------------------
// SpMM2 + bias + fused log_softmax: 16-edge main loop = 4 gather chains/lane
// x2wb rows padded to 64 bf16 = 128 B = one L2 line per edge gather
// ---------------------------------------------------------------------------
__global__ __launch_bounds__(256) void spmm2_kernel(const int* __restrict__ offs,
                                                    const int2* __restrict__ csr,
                                                    const __bf16* __restrict__ x2wb,
                                                    const float* __restrict__ b2,
                                                    float* __restrict__ out, int n) {
  const int lane = threadIdx.x & 63;
  const int wid = threadIdx.x >> 6;
  const int row = blockIdx.x * 4 + wid;
  if (row >= n) return;
  const int s = offs[row], t = offs[row + 1];
  const int grp = lane >> 4, sl = lane & 15;
  const bf16x4* xv = (const bf16x4*)x2wb;  // row stride 16 chunks
  float a0 = 0.f, a1 = 0.f, a2 = 0.f, a3 = 0.f;
  int j = s;
  for (; j + 15 < t; j += 16) {  // 16 edges: 4 unguarded gathers in flight/lane
    int2 ca = csr[j + grp];
    int2 cb = csr[j + 4 + grp];
    int2 cc = csr[j + 8 + grp];
    int2 cd = csr[j + 12 + grp];
    bf16x4 va = xv[(size_t)ca.x * 16 + sl];
    bf16x4 vb = xv[(size_t)cb.x * 16 + sl];
    bf16x4 vc = xv[(size_t)cc.x * 16 + sl];
    bf16x4 vd = xv[(size_t)cd.x * 16 + sl];
    float wa = __int_as_float(ca.y), wb = __int_as_float(cb.y);
    float wc = __int_as_float(cc.y), wd = __int_as_float(cd.y);
    a0 += wa * (float)va[0] + wb * (float)vb[0] + wc * (float)vc[0] + wd * (float)vd[0];
    a1 += wa * (float)va[1] + wb * (float)vb[1] + wc * (float)vc[1] + wd * (float)vd[1];
    a2 += wa * (float)va[2] + wb * (float)vb[2] + wc * (float)vc[2] + wd * (float)vd[2];
    a3 += wa * (float)va[3] + wb * (float)vb[3] + wc * (float)vc[3] + wd * (float)vd[3];
  }
  for (; j + 7 < t; j += 8) {
    int2 ca = csr[j + grp];
    int2 cb = csr[j + 4 + grp];
    bf16x4 va = xv[(size_t)ca.x * 16 + sl];
    bf16x4 vb = xv[(size_t)cb.x * 16 + sl];
    float wa = __int_as_float(ca.y), wb = __int_as_float(cb.y);
    a0 += wa * (float)va[0] + wb * (float)vb[0];
    a1 += wa * (float)va[1] + wb * (float)vb[1];
    a2 += wa * (float)va[2] + wb * (float)vb[2];
    a3 += wa * (float)va[3] + wb * (float)vb[3];
  }
  for (; j < t; j += 4) {
    int jj = j + grp;
    bool ok = jj < t;
    int2 c = csr[ok ? jj : j];
    float w = ok ? __int_as_float(c.y) : 0.f;
    bf16x4 v = xv[(size_t)c.x * 16 + sl];
    a0 += w * (float)v[0];
    a1 += w * (float)v[1];
    a2 += w * (float)v[2];
    a3 += w * (float)v[3];
  }
  a0 += __shfl_xor(a0, 16); a1 += __shfl_xor(a1, 16);
  a2 += __shfl_xor(a2, 16); a3 += __shfl_xor(a3, 16);
  a0 += __shfl_xor(a0, 32); a1 += __shfl_xor(a1, 32);
  a2 += __shfl_xor(a2, 32); a3 += __shfl_xor(a3, 32);

  // fused log_softmax over 40 classes (lanes sl<10 hold 4 valid classes each)
  const float NINF = -__builtin_inff();
  float l0 = NINF, l1 = NINF, l2 = NINF, l3 = NINF;
  if (sl < 10) {
    float4 bb = ((const float4*)b2)[sl];
    l0 = a0 + bb.x; l1 = a1 + bb.y; l2 = a2 + bb.z; l3 = a3 + bb.w;
  }
  float mx = fmaxf(fmaxf(l0, l1), fmaxf(l2, l3));
#pragma unroll
  for (int off = 8; off > 0; off >>= 1) mx = fmaxf(mx, __shfl_xor(mx, off));
  float es = 0.f;
  if (sl < 10) es = expf(l0 - mx) + expf(l1 - mx) + expf(l2 - mx) + expf(l3 - mx);
#pragma unroll
  for (int off = 8; off > 0; off >>= 1) es += __shfl_xor(es, off);
  if (grp == 0 && sl < 10) {
    float lg = mx + logf(es);
    float4 o = make_float4(l0 - lg, l1 - lg, l2 - lg, l3 - lg);
    ((float4*)out)[(size_t)row * 10 + sl] = o;
  }
}

// ---------------------------------------------------------------------------
extern "C" void kernel_launch(void* const* d_in, const int* in_sizes, int n_in,
                              void* d_out, int out_size, void* d_ws, size_t ws_size,
                              hipStream_t stream) {
  const float* x = (const float*)d_in[0];
  const int* erow = (const int*)d_in[1];
  const int* ecol = (const int*)d_in[2];
  const float* ew = (const float*)d_in[3];
  const float* W1 = (const float*)d_in[4];
  const float* b1 = (const float*)d_in[5];
  const float* W2 = (const float*)d_in[6];
  const float* b2 = (const float*)d_in[7];
  const float* dmask = (const float*)d_in[8];

  const int n = in_sizes[0] / NFEAT;       // 100000
  const int e = in_sizes[1];               // 3200000
  const int nb2 = (n + BROWS - 1) >> BSH;  // 196 coarse buckets

  float* out_ls = (float*)d_out;            // [n,40]
  float* x2 = out_ls + (size_t)n * NCLASS;  // [n,128]

  // workspace layout (x2wb aliases tmp: tmp dead before gemm2 writes x2wb)
  uintptr_t p = (uintptr_t)d_ws;
  __bf16* xwb = (__bf16*)p;  p += (size_t)n * NHID * 2;      // 25.6 MB
  __bf16* Btb = (__bf16*)p;  p += (size_t)NHID * NFEAT * 2;  // 128 KB
  __bf16* W2t = (__bf16*)p;  p += (size_t)48 * NHID * 2;     // 12 KB
  int2* csr = (int2*)p;      p += (size_t)e * 8;             // 25.6 MB
  int2* tmp = (int2*)p;      __bf16* x2wb = (__bf16*)p;      // pad-64 rows
  p += (size_t)e * 8;                                        // 25.6 MB (shared)
  int* offs = (int*)p;       p += ((size_t)n + 1) * 4;
  int* bhist = (int*)p;      p += 256 * 4;
  int* bbase = (int*)p;      p += 257 * 4;
  int* bcur = (int*)p;       p += 256 * 4;
  p = (p + 15) & ~(uintptr_t)15;
  unsigned long long* dbits = (unsigned long long*)p;  // n*128 bits = 1.6 MB
  p += (size_t)n * NHID / 8;

  hipMemsetAsync(bhist, 0, 256 * sizeof(int), stream);

  convW1_kernel<<<NFEAT * NHID / 256, 256, 0, stream>>>(W1, Btb);
  convW2_kernel<<<48 * NHID / 256, 256, 0, stream>>>(W2, W2t);
  {
    int total64 = (int)((size_t)n * NHID / 64);  // 200000 waves
    packmask_kernel<<<(total64 + 3) / 4, 256, 0, stream>>>(dmask, dbits, total64);
  }
  gemm1_mfma_kernel<<<(n + 63) / 64, 256, 0, stream>>>(x, Btb, xwb, n);

  hist_kernel<<<1024, 256, 0, stream>>>(erow, bhist, e, nb2);
  bucketscan_kernel<<<1, 256, 0, stream>>>(bhist, bbase, bcur, offs, n, e, nb2);
  partition_kernel<<<(e + PCHUNK - 1) / PCHUNK, 256, 0, stream>>>(erow, ecol, ew, bcur, tmp, e, nb2);
  scatter_kernel<<<nb2, 256, 0, stream>>>(bbase, tmp, csr, offs, n);

  spmm1_kernel<<<(n + 3) / 4, 256, 0, stream>>>(offs, csr, xwb, b1, (const unsigned int*)dbits, x2, n);
  gemm2_mfma_kernel<<<(n + 63) / 64, 256, 0, stream>>>(x2, W2t, x2wb, n);
  spmm2_kernel<<<(n + 3) / 4, 256, 0, stream>>>(offs, csr, x2wb, b2, out_ls, n);
}